// Round 16
// baseline (315.661 us; speedup 1.0000x reference)
//
#include <hip/hip_runtime.h>

// SelfAttention: B=8, S=2048, D=1024, fp32 in/out — ALL-FP16 MFMA pipeline.
// Algebra: S/32 = E·Mt^T·E^T + c_j, Mt[f][e] = (sum_c Wk[c][f]Wq[c][e])/32,
// c = E·(Wk^T bq)/32; per-row terms cancel in softmax.
// NEW core: 256x256 tile, 16 waves (1024 thr, 64x64/wave) = 4 waves/SIMD TLP.
// LDS kh-major: per operand [2 kh][256 r][32 k] u16; chunk(kh)=16KB = one
// 1024-thread global_load_lds. 16B-slot swizzle sigma = r*4 + (ko^((r>>1)&3))
// (self-inverse; 2-way banks = free). 2 phases/tile (kh0, kh1), 2 barriers,
// entry vmcnt(2), mid vmcnt(4) — loads always >=2 in flight.
// Setup: mega-prep (cvts + non-atomic w GEMV), split-K Mt + c GEMV, reduce.
// scores: fp16 s/32 logits; softmax adds mask/32 (fp32); PV fp16 MFMA, f32 out.
// d_ws (u16): scH[32M] | emb16[16M] | WqT[1M] WkT[1M] Wv16[1M] Mt[1M] |
//   G[16M] vT[16M] | MtP fp32[4M] | w[1K f32] c[16K f32].

#define B_SZ 8
#define SEQ  2048
#define DIM  1024
#define MROWS (B_SZ * SEQ)  // 16384

typedef unsigned short u16;
typedef short short8 __attribute__((ext_vector_type(8)));
typedef unsigned short u16x4 __attribute__((ext_vector_type(4)));
typedef float f32x4 __attribute__((ext_vector_type(4)));

__device__ __forceinline__ u16 f2h(float x) {
  _Float16 h = (_Float16)x;
  union { _Float16 f; u16 u; } c; c.f = h; return c.u;
}
__device__ __forceinline__ float h2f(u16 u) {
  union { _Float16 f; u16 u; } c; c.u = u; return (float)c.f;
}

__device__ __forceinline__ int xcd_swz(int x, int nwg) {
  return (x & 7) * (nwg >> 3) + (x >> 3);
}

__device__ __forceinline__ void gload_lds16(const u16* g, u16* l) {
  __builtin_amdgcn_global_load_lds(
      (__attribute__((address_space(1))) void*)(g),
      (__attribute__((address_space(3))) void*)(l), 16, 0, 0);
}

__device__ __forceinline__ f32x4 mfma_f16(short8 a, short8 b, f32x4 c) {
  asm("v_mfma_f32_16x16x32_f16 %0, %1, %2, %0" : "+v"(c) : "v"(a), "v"(b));
  return c;
}

// ================= 256x256 16-wave GEMM core (fp16, kh-major LDS) ==========
// Wave wid (0..15): wm=wid>>2 (row strip*64), wn=wid&3 (col strip*64).
// Per wave per kh: 4 A-frags + 4 B-frags (b128), 16 MFMA (4m x 4n).
// Staging slot t (0..1023) of a 16KB chunk holds logical (r=t>>2,
// ko=(t&3)^((t>>3)&3)); read addr sigma(r,ko)=r*4+(ko^((r>>1)&3)) slots.
// Issue order per tile: Bk0, Ak0, Bk1, Ak1 (issued at ph0 of previous tile).
__device__ __forceinline__ void gemm256_core(const u16* __restrict__ Ag,
                                             const u16* __restrict__ Bg,
                                             int NT, size_t lda, size_t ldb,
                                             u16* sm, f32x4 (&acc)[4][4]) {
  const int tid = threadIdx.x;
  const int lane = tid & 63;
  const int wid = tid >> 6;       // 0..15
  const int wm = wid >> 2;        // 0..3
  const int wn = wid & 3;         // 0..3

  u16* sA = sm;                   // [2 buf][2 kh][8192] u16 (64KB)
  u16* sB = sm + 32768;           // same (64KB)

  // staging decode: thread covers slot tid of each chunk
  const int r_s = tid >> 2;                         // 0..255
  const int ko_s = (tid & 3) ^ ((tid >> 3) & 3);    // logical k-group
  const size_t aoffs = (size_t)r_s * lda + ko_s * 8;
  const size_t boffs = (size_t)r_s * ldb + ko_s * 8;
  const int wdst = wid << 9;                        // wid*512 u16

  // fragment read lane offset (u16): r_lane=(lane&15), ko=lane>>4,
  // sigma*8 = r*32 + (ko^((lane>>1)&3))*8   (row-strip terms added per frag)
  const int lof = ((lane & 15) << 5) + ((((lane >> 4) ^ ((lane >> 1) & 3))) << 3);
  const int abase = (wm << 11) + lof;   // wm*64 rows *32 u16
  const int bbase = (wn << 11) + lof;

#define ISSUE_TILE(nb, kt)                                                        \
  do {                                                                            \
    gload_lds16(Bg + boffs + (size_t)(kt) * 64,      sB + (nb) * 16384 + wdst);   \
    gload_lds16(Ag + aoffs + (size_t)(kt) * 64,      sA + (nb) * 16384 + wdst);   \
    gload_lds16(Bg + boffs + (size_t)(kt) * 64 + 32, sB + (nb) * 16384 + 8192 + wdst); \
    gload_lds16(Ag + aoffs + (size_t)(kt) * 64 + 32, sA + (nb) * 16384 + 8192 + wdst); \
  } while (0)

  // prologue: stage tile 0 into buf 0
  ISSUE_TILE(0, 0);

  int buf = 0;
  for (int kt = 0; kt < NT; ++kt) {
    const bool pre = (kt + 1) < NT;
    const int nb = buf ^ 1;
    // entry: Bk0, Ak0 of this tile must be in LDS (2 oldest); Bk1,Ak1 may fly
    asm volatile("s_waitcnt vmcnt(2)" ::: "memory");
    __builtin_amdgcn_s_barrier();
    asm volatile("" ::: "memory");
    const u16* bufA = sA + buf * 16384;
    const u16* bufB = sB + buf * 16384;
    // ---- phase 0 (kh=0): reads + issue next tile + MFMA
    {
      short8 bf[4];
#pragma unroll
      for (int n = 0; n < 4; ++n)
        bf[n] = *(const short8*)(bufB + bbase + (n << 9));
      if (pre) ISSUE_TILE(nb, kt + 1);
      __builtin_amdgcn_s_setprio(1);
#pragma unroll
      for (int m = 0; m < 4; ++m) {
        short8 af = *(const short8*)(bufA + abase + (m << 9));
#pragma unroll
        for (int n = 0; n < 4; ++n)
          acc[m][n] = mfma_f16(af, bf[n], acc[m][n]);
      }
      __builtin_amdgcn_s_setprio(0);
    }
    // mid: Bk1, Ak1 of this tile must land (oldest 2 of <=6 outstanding)
    if (pre) {
      asm volatile("s_waitcnt vmcnt(4)" ::: "memory");
    } else {
      asm volatile("s_waitcnt vmcnt(0)" ::: "memory");
    }
    __builtin_amdgcn_s_barrier();
    asm volatile("" ::: "memory");
    // ---- phase 1 (kh=1)
    {
      short8 bf[4];
#pragma unroll
      for (int n = 0; n < 4; ++n)
        bf[n] = *(const short8*)(bufB + 8192 + bbase + (n << 9));
      __builtin_amdgcn_s_setprio(1);
#pragma unroll
      for (int m = 0; m < 4; ++m) {
        short8 af = *(const short8*)(bufA + 8192 + abase + (m << 9));
#pragma unroll
        for (int n = 0; n < 4; ++n)
          acc[m][n] = mfma_f16(af, bf[n], acc[m][n]);
      }
      __builtin_amdgcn_s_setprio(0);
    }
    buf ^= 1;
  }
  asm volatile("s_nop 7\n\ts_nop 7\n\ts_nop 7" ::);
#undef ISSUE_TILE
}

// ======== 128x128 4-wave core (r0-verified structure, f16) ===================
__device__ __forceinline__ void gemm128_core(const u16* A, const u16* Bt, int K,
                                             int lda, int ldb, f32x4 (&acc)[4][4],
                                             u16* sA, u16* sB) {
  const int tid = threadIdx.x;
  const int lane = tid & 63;
  const int wid = tid >> 6;
  const int wr = wid >> 1;
  const int wc = wid & 1;
  const int srow = tid >> 2;
  const int scol = (tid & 3) << 3;
  const u16* ga0 = A + (size_t)srow * lda + scol;
  const u16* ga1 = A + (size_t)(srow + 64) * lda + scol;
  const u16* gb0 = Bt + (size_t)srow * ldb + scol;
  const u16* gb1 = Bt + (size_t)(srow + 64) * ldb + scol;
  u16* la0 = sA + (wid << 9);
  u16* la1 = sA + 2048 + (wid << 9);
  u16* lb0 = sB + (wid << 9);
  u16* lb1 = sB + 2048 + (wid << 9);
  const u16* pa = sA + (size_t)((wr << 6) + (lane & 15)) * 32 + ((lane >> 4) << 3);
  const u16* pb = sB + (size_t)((wc << 6) + (lane & 15)) * 32 + ((lane >> 4) << 3);
  const int ksteps = K >> 5;
  for (int kt = 0; kt < ksteps; ++kt) {
    gload_lds16(ga0, la0);
    gload_lds16(ga1, la1);
    gload_lds16(gb0, lb0);
    gload_lds16(gb1, lb1);
    ga0 += 32; ga1 += 32; gb0 += 32; gb1 += 32;
    __syncthreads();
    short8 a[4], b[4];
#pragma unroll
    for (int i = 0; i < 4; ++i) a[i] = *(const short8*)(pa + (i << 9));
#pragma unroll
    for (int i = 0; i < 4; ++i) b[i] = *(const short8*)(pb + (i << 9));
#pragma unroll
    for (int mi = 0; mi < 4; ++mi)
#pragma unroll
      for (int ni = 0; ni < 4; ++ni)
        acc[mi][ni] = mfma_f16(a[mi], b[ni], acc[mi][ni]);
    __syncthreads();
  }
  asm volatile("s_nop 7\n\ts_nop 7\n\ts_nop 7" ::);
}

// ---- MEGA-PREP (grid 17952): emb cvt | WqT/WkT transpose-cvt | Wv cvt |
//      w GEMV (32 blocks, non-atomic: 8 row-groups x 32 e-lanes, LDS reduce)
__global__ __launch_bounds__(256) void prep_kernel(const float* __restrict__ emb,
                                                   const float* __restrict__ Wq,
                                                   const float* __restrict__ Wk,
                                                   const float* __restrict__ Wv,
                                                   const float* __restrict__ bq,
                                                   u16* __restrict__ emb16,
                                                   u16* __restrict__ WqT,
                                                   u16* __restrict__ WkT,
                                                   u16* __restrict__ Wv16,
                                                   float* __restrict__ w) {
  __shared__ float t[64][65];
  const int b = blockIdx.x;
  const int tid = threadIdx.x;
  if (b < 16384) {
    int i = b * 256 + tid;
    float4 v = ((const float4*)emb)[i];
    u16x4 o;
    o[0] = f2h(v.x); o[1] = f2h(v.y); o[2] = f2h(v.z); o[3] = f2h(v.w);
    ((u16x4*)emb16)[i] = o;
  } else if (b < 16896) {
    const int b2 = b - 16384;
    const float* src = (b2 >> 8) ? Wk : Wq;
    u16* dst = (b2 >> 8) ? WkT : WqT;
    const int rem = b2 & 255;
    const int r0 = (rem >> 4) * 64;
    const int c0 = (rem & 15) * 64;
    const int tr = tid >> 4;
    const int c4 = (tid & 15) << 2;
#pragma unroll
    for (int i = 0; i < 4; ++i) {
      float4 x = *(const float4*)(src + (size_t)(r0 + tr + 16 * i) * 1024 + c0 + c4);
      t[tr + 16 * i][c4 + 0] = x.x;
      t[tr + 16 * i][c4 + 1] = x.y;
      t[tr + 16 * i][c4 + 2] = x.z;
      t[tr + 16 * i][c4 + 3] = x.w;
    }
    __syncthreads();
#pragma unroll
    for (int i = 0; i < 4; ++i) {
      int dr = tr + 16 * i;
      u16x4 y;
      y[0] = f2h(t[c4 + 0][dr]);
      y[1] = f2h(t[c4 + 1][dr]);
      y[2] = f2h(t[c4 + 2][dr]);
      y[3] = f2h(t[c4 + 3][dr]);
      *(u16x4*)(dst + (size_t)(c0 + dr) * 1024 + r0 + c4) = y;
    }
  } else if (b < 17920) {
    int i = (b - 16896) * 256 + tid;
    float4 v = ((const float4*)Wv)[i];
    u16x4 o;
    o[0] = f2h(v.x); o[1] = f2h(v.y); o[2] = f2h(v.z); o[3] = f2h(v.w);
    ((u16x4*)Wv16)[i] = o;
  } else {
    const int wb = b - 17920;          // 0..31
    const int el = tid & 31;
    const int rg = tid >> 5;
    const int e = wb * 32 + el;
    float s = 0.f;
    const float* col = Wk + e;
#pragma unroll 4
    for (int r = rg * 128; r < rg * 128 + 128; ++r)
      s += col[(size_t)r * 1024] * bq[r];
    float* red = &t[0][0];
    red[rg * 32 + el] = s;
    __syncthreads();
    if (tid < 32) {
      float a = 0.f;
#pragma unroll
      for (int g = 0; g < 8; ++g) a += red[g * 32 + tid];
      w[wb * 32 + tid] = a * 0.03125f;
    }
  }
}

// ---- launch 2 (grid 4352): c GEMV (wave-per-row) | Mt split-K partials
__global__ __launch_bounds__(256) void cmt_kernel(const u16* __restrict__ emb16,
                                                  const u16* __restrict__ WqT,
                                                  const u16* __restrict__ WkT,
                                                  const float* __restrict__ w,
                                                  float* __restrict__ c,
                                                  float* __restrict__ MtP) {
  __shared__ __align__(16) u16 smem[8192];
  const int b = blockIdx.x;
  const int tid = threadIdx.x;
  if (b < 4096) {
    float* sw = (float*)smem;
    for (int i = tid; i < 1024; i += 256) sw[i] = w[i];
    __syncthreads();
    const int wv = tid >> 6, lane = tid & 63;
    const int r = b * 4 + wv;
    const u16* row = emb16 + (size_t)r * 1024;
    float s = 0.f;
#pragma unroll
    for (int it = 0; it < 2; ++it) {
      int d = lane * 8 + it * 512;
      short8 v = *(const short8*)(row + d);
#pragma unroll
      for (int j = 0; j < 8; ++j) s += h2f((u16)v[j]) * sw[d + j];
    }
#pragma unroll
    for (int off = 1; off < 64; off <<= 1) s += __shfl_xor(s, off);
    if (lane == 0) c[r] = s;
  } else {
    const int b2 = b - 4096;
    const int tile = b2 >> 2;
    const int kc = b2 & 3;
    const int m0 = (tile >> 3) * 128;
    const int n0 = (tile & 7) * 128;
    f32x4 acc[4][4] = {};
    gemm128_core(WkT + (size_t)m0 * 1024 + kc * 256,
                 WqT + (size_t)n0 * 1024 + kc * 256, 256, 1024, 1024,
                 acc, smem, smem + 4096);
    const int lane = tid & 63, wid = tid >> 6;
    const int wr = wid >> 1, wc = wid & 1;
    float* plane = MtP + (size_t)kc * 1024 * 1024;
#pragma unroll
    for (int mi = 0; mi < 4; ++mi)
#pragma unroll
      for (int ni = 0; ni < 4; ++ni)
#pragma unroll
        for (int j = 0; j < 4; ++j) {
          int row = m0 + (wr << 6) + mi * 16 + ((lane >> 4) << 2) + j;
          int col = n0 + (wc << 6) + ni * 16 + (lane & 15);
          plane[(size_t)row * 1024 + col] = acc[mi][ni][j];
        }
  }
}

// ---- Mt reduce: Mt = fp16( (P0+P1+P2+P3) / 32 )
__global__ __launch_bounds__(256) void mtred_kernel(const float* __restrict__ MtP,
                                                    u16* __restrict__ Mt) {
  const size_t i = (size_t)blockIdx.x * 1024 + threadIdx.x * 4;
  float4 a = *(const float4*)(MtP + i);
  float4 b = *(const float4*)(MtP + 1048576 + i);
  float4 cc = *(const float4*)(MtP + 2097152 + i);
  float4 d = *(const float4*)(MtP + 3145728 + i);
  u16x4 o;
  o[0] = f2h((a.x + b.x + cc.x + d.x) * 0.03125f);
  o[1] = f2h((a.y + b.y + cc.y + d.y) * 0.03125f);
  o[2] = f2h((a.z + b.z + cc.z + d.z) * 0.03125f);
  o[3] = f2h((a.w + b.w + cc.w + d.w) * 0.03125f);
  *(u16x4*)(Mt + i) = o;
}

// ---- merged G + vT (flat grid 512, XCD-swizzled, uniform NT=16), 1024 thr
__global__ __launch_bounds__(1024) void proj256_kernel(const u16* __restrict__ emb16,
                                                       const u16* __restrict__ Mt,
                                                       const u16* __restrict__ Wv16,
                                                       const float* __restrict__ bv,
                                                       u16* __restrict__ G,
                                                       u16* __restrict__ vT) {
  __shared__ __align__(16) u16 sm[65536];
  const int wg = xcd_swz(blockIdx.x, 512);
  const int lane = threadIdx.x & 63, wid = threadIdx.x >> 6;
  f32x4 acc[4][4] = {};
  const int rbw = ((wid >> 2) << 6) + ((lane >> 4) << 2);
  const int cbw = ((wid & 3) << 6) + (lane & 15);
  if (wg < 256) {
    const int m0 = (wg >> 2) * 256;
    const int n0 = (wg & 3) * 256;
    gemm256_core(emb16 + (size_t)m0 * 1024, Mt + (size_t)n0 * 1024, 16, 1024, 1024,
                 sm, acc);
    const int rb = m0 + rbw;
    const int cb = n0 + cbw;
#pragma unroll
    for (int m = 0; m < 4; ++m)
#pragma unroll
      for (int n = 0; n < 4; ++n)
#pragma unroll
        for (int j = 0; j < 4; ++j)
          G[(size_t)(rb + m * 16 + j) * 1024 + (cb + n * 16)] = f2h(acc[m][n][j]);
  } else {
    const int r = wg - 256;
    const int m0 = (r & 3) * 256;   // d
    const int n0 = (r >> 2) * 256;  // global rows
    gemm256_core(Wv16 + (size_t)m0 * 1024, emb16 + (size_t)n0 * 1024, 16, 1024, 1024,
                 sm, acc);
    const int rb = m0 + rbw;
    const int cb = n0 + cbw;
#pragma unroll
    for (int m = 0; m < 4; ++m)
#pragma unroll
      for (int n = 0; n < 4; ++n)
#pragma unroll
        for (int j = 0; j < 4; ++j) {
          int d = rb + m * 16 + j;
          int kg = cb + n * 16;
          int bi = kg >> 11, s = kg & 2047;
          vT[((size_t)bi << 21) + ((size_t)d << 11) + s] = f2h(acc[m][n][j] + bv[d]);
        }
  }
}

// ---- scores: scH = fp16( G·E^T + c_col ), 1024 thr
__global__ __launch_bounds__(1024) void scores256_kernel(const u16* __restrict__ G,
                                                         const u16* __restrict__ emb16,
                                                         const float* __restrict__ c,
                                                         u16* __restrict__ scH) {
  __shared__ __align__(16) u16 sm[65536];
  const int wg = xcd_swz(blockIdx.x, 512);
  const int b = wg >> 6;
  const int m0 = ((wg >> 3) & 7) * 256;
  const int n0 = (wg & 7) * 256;
  f32x4 acc[4][4] = {};
  gemm256_core(G + ((size_t)b * SEQ + m0) * DIM, emb16 + ((size_t)b * SEQ + n0) * DIM,
               16, DIM, DIM, sm, acc);
  const int lane = threadIdx.x & 63, wid = threadIdx.x >> 6;
  const int rb = m0 + ((wid >> 2) << 6) + ((lane >> 4) << 2);
  const int cb = n0 + ((wid & 3) << 6) + (lane & 15);
  float cn[4];
#pragma unroll
  for (int n = 0; n < 4; ++n) cn[n] = c[(size_t)b * SEQ + cb + n * 16];
#pragma unroll
  for (int m = 0; m < 4; ++m)
#pragma unroll
    for (int n = 0; n < 4; ++n)
#pragma unroll
      for (int j = 0; j < 4; ++j) {
        size_t idx = ((size_t)b * SEQ + rb + m * 16 + j) * SEQ + (cb + n * 16);
        scH[idx] = f2h(acc[m][n][j] + cn[n]);
      }
}

// ---- softmax: f = scH + mask/32 (fp32 math), probs fp16 in place
__global__ __launch_bounds__(256) void softmax_kernel(u16* __restrict__ scH,
                                                      const float* __restrict__ mask) {
  __shared__ float red[8];
  const size_t row = blockIdx.x;
  u16* rowp = scH + row * SEQ;
  const float* mrow = mask + row * SEQ;
  const int tid = threadIdx.x;
  short8 raw = *(const short8*)(rowp + tid * 8);
  float4 m0 = ((const float4*)mrow)[2 * tid];
  float4 m1 = ((const float4*)mrow)[2 * tid + 1];
  float mk[8] = {m0.x, m0.y, m0.z, m0.w, m1.x, m1.y, m1.z, m1.w};
  float f[8];
#pragma unroll
  for (int j = 0; j < 8; ++j) f[j] = h2f((u16)raw[j]) + mk[j] * 0.03125f;
  float mx = f[0];
#pragma unroll
  for (int j = 1; j < 8; ++j) mx = fmaxf(mx, f[j]);
#pragma unroll
  for (int off = 1; off < 64; off <<= 1) mx = fmaxf(mx, __shfl_xor(mx, off));
  const int wid = tid >> 6, lane = tid & 63;
  if (lane == 0) red[wid] = mx;
  __syncthreads();
  mx = fmaxf(fmaxf(red[0], red[1]), fmaxf(red[2], red[3]));
  float e[8];
  float s = 0.f;
#pragma unroll
  for (int j = 0; j < 8; ++j) {
    e[j] = __expf(f[j] - mx);
    s += e[j];
  }
#pragma unroll
  for (int off = 1; off < 64; off <<= 1) s += __shfl_xor(s, off);
  if (lane == 0) red[4 + wid] = s;
  __syncthreads();
  s = (red[4] + red[5]) + (red[6] + red[7]);
  const float inv = 1.f / s;
  short8 o;
#pragma unroll
  for (int j = 0; j < 8; ++j) o[j] = (short)f2h(e[j] * inv);
  *(short8*)(rowp + tid * 8) = o;
}

// ---- PV: out = probs @ v^T, 1024 thr
__global__ __launch_bounds__(1024) void pv256_kernel(const u16* __restrict__ pr,
                                                     const u16* __restrict__ vt,
                                                     float* __restrict__ out) {
  __shared__ __align__(16) u16 sm[65536];
  const int wg = xcd_swz(blockIdx.x, 256);
  const int b = wg >> 5;
  const int m0 = ((wg >> 2) & 7) * 256;
  const int n0 = (wg & 3) * 256;
  f32x4 acc[4][4] = {};
  gemm256_core(pr + ((size_t)b * SEQ + m0) * SEQ, vt + ((size_t)b * DIM + n0) * SEQ,
               32, SEQ, SEQ, sm, acc);
  const int lane = threadIdx.x & 63, wid = threadIdx.x >> 6;
  const int rb = m0 + ((wid >> 2) << 6) + ((lane >> 4) << 2);
  const int cb = n0 + ((wid & 3) << 6) + (lane & 15);
#pragma unroll
  for (int m = 0; m < 4; ++m)
#pragma unroll
    for (int n = 0; n < 4; ++n)
#pragma unroll
      for (int j = 0; j < 4; ++j)
        out[((size_t)b * SEQ + rb + m * 16 + j) * DIM + (cb + n * 16)] = acc[m][n][j];
}

extern "C" void kernel_launch(void* const* d_in, const int* in_sizes, int n_in,
                              void* d_out, int out_size, void* d_ws, size_t ws_size,
                              hipStream_t stream) {
  const float* emb  = (const float*)d_in[0];
  const float* mask = (const float*)d_in[1];
  const float* Wq   = (const float*)d_in[2];
  const float* bq   = (const float*)d_in[3];
  const float* Wk   = (const float*)d_in[4];
  const float* bk   = (const float*)d_in[5];  // unused: row-terms cancel in softmax
  const float* Wv   = (const float*)d_in[6];
  const float* bv   = (const float*)d_in[7];
  float* out = (float*)d_out;
  (void)bk;

  const size_t M1 = 1024 * 1024;
  u16* scH   = (u16*)d_ws;              // 32M u16
  u16* emb16 = scH + 32 * M1;           // 16M
  u16* WqT   = emb16 + 16 * M1;         // 1M
  u16* WkT   = WqT + M1;                // 1M
  u16* Wv16  = WkT + M1;                // 1M
  u16* Mt    = Wv16 + M1;               // 1M
  u16* G     = Mt + M1;                 // 16M
  u16* vT    = G + 16 * M1;             // 16M
  float* MtP = (float*)(vT + 16 * M1);  // 4M fp32
  float* w   = MtP + 4 * M1;            // 1K fp32
  float* c   = w + 1024;                // 16K fp32

  prep_kernel<<<17952, 256, 0, stream>>>(emb, Wq, Wk, Wv, bq, emb16, WqT, WkT, Wv16, w);
  cmt_kernel<<<4352, 256, 0, stream>>>(emb16, WqT, WkT, w, c, MtP);
  mtred_kernel<<<1024, 256, 0, stream>>>(MtP, Mt);

  proj256_kernel<<<512, 1024, 0, stream>>>(emb16, Mt, Wv16, bv, G, vT);

  scores256_kernel<<<512, 1024, 0, stream>>>(G, emb16, c, scH);
  softmax_kernel<<<MROWS, 256, 0, stream>>>(scH, mask);
  pv256_kernel<<<256, 1024, 0, stream>>>((const u16*)scH, vT, out);
}

// Round 17
// 297.480 us; speedup vs baseline: 1.0611x; 1.0611x over previous
//
#include <hip/hip_runtime.h>

// SelfAttention: B=8, S=2048, D=1024, fp32 in/out — ALL-FP16 MFMA pipeline.
// Algebra: S/32 = E·Mt^T·E^T + c_j, Mt[f][e] = (sum_c Wk[c][f]Wq[c][e])/32,
// c = E·(Wk^T bq)/32; per-row terms cancel in softmax (q/k projections removed).
// Core: 256x256-tile 8-wave BK=64 double-buffered, per-phase barriers (r12/r13
// structure, best measured) with kh-OUTER MFMA ordering: 8 independent MFMAs
// between successive updates of the same accumulator (breaks RAW adjacency).
// Waits: entry vmcnt(2), mid vmcnt(4). Swizzled LDS via pre-swizzled global
// staging; XCD-chunked block swizzle.
// Setup: mega-prep (cvts + non-atomic w GEMV), split-K Mt + c GEMV, tiny reduce.
// scores: fp16 s/32 logits; softmax adds mask/32 (fp32); PV fp16 MFMA, fp32 out.
// d_ws (u16): scH[32M] | emb16[16M] | WqT[1M] WkT[1M] Wv16[1M] Mt[1M] |
//   G[16M] vT[16M] | MtP fp32[4M] | w[1K f32] c[16K f32].

#define B_SZ 8
#define SEQ  2048
#define DIM  1024
#define MROWS (B_SZ * SEQ)  // 16384

typedef unsigned short u16;
typedef short short8 __attribute__((ext_vector_type(8)));
typedef unsigned short u16x4 __attribute__((ext_vector_type(4)));
typedef float f32x4 __attribute__((ext_vector_type(4)));

__device__ __forceinline__ u16 f2h(float x) {
  _Float16 h = (_Float16)x;
  union { _Float16 f; u16 u; } c; c.f = h; return c.u;
}
__device__ __forceinline__ float h2f(u16 u) {
  union { _Float16 f; u16 u; } c; c.u = u; return (float)c.f;
}

__device__ __forceinline__ int xcd_swz(int x, int nwg) {
  return (x & 7) * (nwg >> 3) + (x >> 3);
}

__device__ __forceinline__ void gload_lds16(const u16* g, u16* l) {
  __builtin_amdgcn_global_load_lds(
      (__attribute__((address_space(1))) void*)(g),
      (__attribute__((address_space(3))) void*)(l), 16, 0, 0);
}

__device__ __forceinline__ f32x4 mfma_f16(short8 a, short8 b, f32x4 c) {
  asm("v_mfma_f32_16x16x32_f16 %0, %1, %2, %0" : "+v"(c) : "v"(a), "v"(b));
  return c;
}

// ================= 256x256 8-wave GEMM core (fp16), per-phase barriers ======
// Consumption: ph0/1 need B*,A0(wm0)/A2(wm1); ph2/3 need A1(wm0)/A3(wm1).
// Next-tile issue: ph0 B0,B1 | ph1 B2,B3 | ph2 A0,A2 | ph3 A1,A3 (FIFO).
// Waits: entry vmcnt(2) (own A1,A3 may fly); pre-ph2 vmcnt(4) when prefetching
// (allows the 4 new B loads; forces old A1,A3 landed), else vmcnt(0).
// MFMA ordering: kh outermost -> same-acc updates separated by 8 independents.
#define PHASE_MFMA(mb, af)                                        \
  __builtin_amdgcn_s_setprio(1);                                  \
  _Pragma("unroll")                                               \
  for (int h = 0; h < 2; ++h)                                     \
    _Pragma("unroll")                                             \
    for (int m = 0; m < 2; ++m)                                   \
      _Pragma("unroll")                                           \
      for (int n = 0; n < 4; ++n)                                 \
        acc[(mb) + m][n] = mfma_f16(af[m][h], bf[n][h], acc[(mb) + m][n]); \
  __builtin_amdgcn_s_setprio(0)

__device__ __forceinline__ void gemm256_core(const u16* __restrict__ Ag,
                                             const u16* __restrict__ Bg,
                                             int NT, size_t lda, size_t ldb,
                                             u16* sm, f32x4 (&acc)[8][4]) {
  const int tid = threadIdx.x;
  const int lane = tid & 63;
  const int wid = tid >> 6;
  const int wm8 = (wid >> 2) << 3;
  const int wn4 = (wid & 3) << 2;

  u16* sA = sm;
  u16* sB = sm + 32768;

  const int bb = (lane << 4) ^ (((lane >> 5) & 1) << 5);
  const int rins = bb >> 6;
  const int cins = (bb & 63) >> 1;
  const int s0 = wid, s1 = 8 + wid, s2 = 16 + wid, s3 = 24 + wid;
  const size_t aoff0 = (size_t)((s0 >> 1) * 16 + rins) * lda + ((s0 & 1) * 32 + cins);
  const size_t aoff1 = (size_t)((s1 >> 1) * 16 + rins) * lda + ((s1 & 1) * 32 + cins);
  const size_t aoff2 = (size_t)((s2 >> 1) * 16 + rins) * lda + ((s2 & 1) * 32 + cins);
  const size_t aoff3 = (size_t)((s3 >> 1) * 16 + rins) * lda + ((s3 & 1) * 32 + cins);
  const size_t boff0 = (size_t)((s0 >> 1) * 16 + rins) * ldb + ((s0 & 1) * 32 + cins);
  const size_t boff1 = (size_t)((s1 >> 1) * 16 + rins) * ldb + ((s1 & 1) * 32 + cins);
  const size_t boff2 = (size_t)((s2 >> 1) * 16 + rins) * ldb + ((s2 & 1) * 32 + cins);
  const size_t boff3 = (size_t)((s3 >> 1) * 16 + rins) * ldb + ((s3 & 1) * 32 + cins);
  const int wid512 = wid << 9;

  const int lof = ((lane & 15) << 6) + ((lane >> 4) << 4);
  const int loe = (lof ^ (((lane >> 3) & 1) << 5)) >> 1;

#define ISSUE_A(j, nb, kt) \
  gload_lds16(Ag + aoff##j + (size_t)(kt) * 64, sA + (nb) * 16384 + (j) * 4096 + wid512)
#define ISSUE_B(j, nb, kt) \
  gload_lds16(Bg + boff##j + (size_t)(kt) * 64, sB + (nb) * 16384 + (j) * 4096 + wid512)

  // prologue: stage tile 0 into buf 0 in steady-state FIFO order
  ISSUE_B(0, 0, 0); ISSUE_B(1, 0, 0); ISSUE_B(2, 0, 0); ISSUE_B(3, 0, 0);
  ISSUE_A(0, 0, 0); ISSUE_A(2, 0, 0); ISSUE_A(1, 0, 0); ISSUE_A(3, 0, 0);

  int buf = 0;
  for (int kt = 0; kt < NT; ++kt) {
    const int nk = kt + 1;
    const bool pre = nk < NT;
    const int nb = buf ^ 1;
    // tile entry: B0-3, A0, A2 landed (all waves); own A1,A3 may fly
    asm volatile("s_waitcnt vmcnt(2)" ::: "memory");
    __builtin_amdgcn_s_barrier();
    asm volatile("" ::: "memory");
    const u16* bufA = sA + buf * 16384;
    const u16* bufB = sB + buf * 16384;
    short8 bf[4][2];
    // ---- phase 0: reads bf + A(m0,m1); issue B0,B1; MFMA m0,m1
    {
#pragma unroll
      for (int n = 0; n < 4; ++n) {
        bf[n][0] = *(const short8*)(bufB + (wn4 + n) * 1024 + loe);
        bf[n][1] = *(const short8*)(bufB + (wn4 + n) * 1024 + 512 + loe);
      }
      short8 af[2][2];
#pragma unroll
      for (int m = 0; m < 2; ++m) {
        af[m][0] = *(const short8*)(bufA + (wm8 + m) * 1024 + loe);
        af[m][1] = *(const short8*)(bufA + (wm8 + m) * 1024 + 512 + loe);
      }
      if (pre) { ISSUE_B(0, nb, nk); ISSUE_B(1, nb, nk); }
      PHASE_MFMA(0, af);
    }
    __builtin_amdgcn_s_barrier();
    asm volatile("" ::: "memory");
    // ---- phase 1: reads A(m2,m3); issue B2,B3; MFMA m2,m3
    {
      short8 af[2][2];
#pragma unroll
      for (int m = 0; m < 2; ++m) {
        af[m][0] = *(const short8*)(bufA + (wm8 + 2 + m) * 1024 + loe);
        af[m][1] = *(const short8*)(bufA + (wm8 + 2 + m) * 1024 + 512 + loe);
      }
      if (pre) { ISSUE_B(2, nb, nk); ISSUE_B(3, nb, nk); }
      PHASE_MFMA(2, af);
    }
    // mid-tile: old A1,A3 must land for ph2/3 reads (all waves)
    if (pre) {
      asm volatile("s_waitcnt vmcnt(4)" ::: "memory");
    } else {
      asm volatile("s_waitcnt vmcnt(0)" ::: "memory");
    }
    __builtin_amdgcn_s_barrier();
    asm volatile("" ::: "memory");
    // ---- phase 2: reads A(m4,m5); issue A0,A2; MFMA m4,m5
    {
      short8 af[2][2];
#pragma unroll
      for (int m = 0; m < 2; ++m) {
        af[m][0] = *(const short8*)(bufA + (wm8 + 4 + m) * 1024 + loe);
        af[m][1] = *(const short8*)(bufA + (wm8 + 4 + m) * 1024 + 512 + loe);
      }
      if (pre) { ISSUE_A(0, nb, nk); ISSUE_A(2, nb, nk); }
      PHASE_MFMA(4, af);
    }
    __builtin_amdgcn_s_barrier();
    asm volatile("" ::: "memory");
    // ---- phase 3: reads A(m6,m7); issue A1,A3; MFMA m6,m7
    {
      short8 af[2][2];
#pragma unroll
      for (int m = 0; m < 2; ++m) {
        af[m][0] = *(const short8*)(bufA + (wm8 + 6 + m) * 1024 + loe);
        af[m][1] = *(const short8*)(bufA + (wm8 + 6 + m) * 1024 + 512 + loe);
      }
      if (pre) { ISSUE_A(1, nb, nk); ISSUE_A(3, nb, nk); }
      PHASE_MFMA(6, af);
    }
    buf ^= 1;
  }
  asm volatile("s_nop 7\n\ts_nop 7\n\ts_nop 7" ::);
#undef ISSUE_A
#undef ISSUE_B
}

// ======== 128x128 4-wave core (r0-verified structure, f16) ===================
__device__ __forceinline__ void gemm128_core(const u16* A, const u16* Bt, int K,
                                             int lda, int ldb, f32x4 (&acc)[4][4],
                                             u16* sA, u16* sB) {
  const int tid = threadIdx.x;
  const int lane = tid & 63;
  const int wid = tid >> 6;
  const int wr = wid >> 1;
  const int wc = wid & 1;
  const int srow = tid >> 2;
  const int scol = (tid & 3) << 3;
  const u16* ga0 = A + (size_t)srow * lda + scol;
  const u16* ga1 = A + (size_t)(srow + 64) * lda + scol;
  const u16* gb0 = Bt + (size_t)srow * ldb + scol;
  const u16* gb1 = Bt + (size_t)(srow + 64) * ldb + scol;
  u16* la0 = sA + (wid << 9);
  u16* la1 = sA + 2048 + (wid << 9);
  u16* lb0 = sB + (wid << 9);
  u16* lb1 = sB + 2048 + (wid << 9);
  const u16* pa = sA + (size_t)((wr << 6) + (lane & 15)) * 32 + ((lane >> 4) << 3);
  const u16* pb = sB + (size_t)((wc << 6) + (lane & 15)) * 32 + ((lane >> 4) << 3);
  const int ksteps = K >> 5;
  for (int kt = 0; kt < ksteps; ++kt) {
    gload_lds16(ga0, la0);
    gload_lds16(ga1, la1);
    gload_lds16(gb0, lb0);
    gload_lds16(gb1, lb1);
    ga0 += 32; ga1 += 32; gb0 += 32; gb1 += 32;
    __syncthreads();
    short8 a[4], b[4];
#pragma unroll
    for (int i = 0; i < 4; ++i) a[i] = *(const short8*)(pa + (i << 9));
#pragma unroll
    for (int i = 0; i < 4; ++i) b[i] = *(const short8*)(pb + (i << 9));
#pragma unroll
    for (int mi = 0; mi < 4; ++mi)
#pragma unroll
      for (int ni = 0; ni < 4; ++ni)
        acc[mi][ni] = mfma_f16(a[mi], b[ni], acc[mi][ni]);
    __syncthreads();
  }
  asm volatile("s_nop 7\n\ts_nop 7\n\ts_nop 7" ::);
}

// ---- MEGA-PREP (grid 17952): emb cvt | WqT/WkT transpose-cvt | Wv cvt |
//      w GEMV (32 blocks, non-atomic: 8 row-groups x 32 e-lanes, LDS reduce)
__global__ __launch_bounds__(256) void prep_kernel(const float* __restrict__ emb,
                                                   const float* __restrict__ Wq,
                                                   const float* __restrict__ Wk,
                                                   const float* __restrict__ Wv,
                                                   const float* __restrict__ bq,
                                                   u16* __restrict__ emb16,
                                                   u16* __restrict__ WqT,
                                                   u16* __restrict__ WkT,
                                                   u16* __restrict__ Wv16,
                                                   float* __restrict__ w) {
  __shared__ float t[64][65];
  const int b = blockIdx.x;
  const int tid = threadIdx.x;
  if (b < 16384) {
    int i = b * 256 + tid;
    float4 v = ((const float4*)emb)[i];
    u16x4 o;
    o[0] = f2h(v.x); o[1] = f2h(v.y); o[2] = f2h(v.z); o[3] = f2h(v.w);
    ((u16x4*)emb16)[i] = o;
  } else if (b < 16896) {
    const int b2 = b - 16384;
    const float* src = (b2 >> 8) ? Wk : Wq;
    u16* dst = (b2 >> 8) ? WkT : WqT;
    const int rem = b2 & 255;
    const int r0 = (rem >> 4) * 64;
    const int c0 = (rem & 15) * 64;
    const int tr = tid >> 4;
    const int c4 = (tid & 15) << 2;
#pragma unroll
    for (int i = 0; i < 4; ++i) {
      float4 x = *(const float4*)(src + (size_t)(r0 + tr + 16 * i) * 1024 + c0 + c4);
      t[tr + 16 * i][c4 + 0] = x.x;
      t[tr + 16 * i][c4 + 1] = x.y;
      t[tr + 16 * i][c4 + 2] = x.z;
      t[tr + 16 * i][c4 + 3] = x.w;
    }
    __syncthreads();
#pragma unroll
    for (int i = 0; i < 4; ++i) {
      int dr = tr + 16 * i;
      u16x4 y;
      y[0] = f2h(t[c4 + 0][dr]);
      y[1] = f2h(t[c4 + 1][dr]);
      y[2] = f2h(t[c4 + 2][dr]);
      y[3] = f2h(t[c4 + 3][dr]);
      *(u16x4*)(dst + (size_t)(c0 + dr) * 1024 + r0 + c4) = y;
    }
  } else if (b < 17920) {
    int i = (b - 16896) * 256 + tid;
    float4 v = ((const float4*)Wv)[i];
    u16x4 o;
    o[0] = f2h(v.x); o[1] = f2h(v.y); o[2] = f2h(v.z); o[3] = f2h(v.w);
    ((u16x4*)Wv16)[i] = o;
  } else {
    // w GEMV, non-atomic: block owns e in [wb*32, wb*32+32); 8 row-groups.
    const int wb = b - 17920;          // 0..31
    const int el = tid & 31;           // e-lane
    const int rg = tid >> 5;           // 0..7
    const int e = wb * 32 + el;
    float s = 0.f;
    const float* col = Wk + e;
#pragma unroll 4
    for (int r = rg * 128; r < rg * 128 + 128; ++r)
      s += col[(size_t)r * 1024] * bq[r];
    float* red = &t[0][0];             // reuse shared (branch-exclusive)
    red[rg * 32 + el] = s;
    __syncthreads();
    if (tid < 32) {
      float a = 0.f;
#pragma unroll
      for (int g = 0; g < 8; ++g) a += red[g * 32 + tid];
      w[wb * 32 + tid] = a * 0.03125f;
    }
  }
}

// ---- launch 2 (grid 4352): c GEMV (wave-per-row) | Mt split-K partials
__global__ __launch_bounds__(256) void cmt_kernel(const u16* __restrict__ emb16,
                                                  const u16* __restrict__ WqT,
                                                  const u16* __restrict__ WkT,
                                                  const float* __restrict__ w,
                                                  float* __restrict__ c,
                                                  float* __restrict__ MtP) {
  __shared__ __align__(16) u16 smem[8192];
  const int b = blockIdx.x;
  const int tid = threadIdx.x;
  if (b < 4096) {
    float* sw = (float*)smem;
    for (int i = tid; i < 1024; i += 256) sw[i] = w[i];
    __syncthreads();
    const int wv = tid >> 6, lane = tid & 63;
    const int r = b * 4 + wv;
    const u16* row = emb16 + (size_t)r * 1024;
    float s = 0.f;
#pragma unroll
    for (int it = 0; it < 2; ++it) {
      int d = lane * 8 + it * 512;
      short8 v = *(const short8*)(row + d);
#pragma unroll
      for (int j = 0; j < 8; ++j) s += h2f((u16)v[j]) * sw[d + j];
    }
#pragma unroll
    for (int off = 1; off < 64; off <<= 1) s += __shfl_xor(s, off);
    if (lane == 0) c[r] = s;
  } else {
    const int b2 = b - 4096;
    const int tile = b2 >> 2;
    const int kc = b2 & 3;
    const int m0 = (tile >> 3) * 128;
    const int n0 = (tile & 7) * 128;
    f32x4 acc[4][4] = {};
    gemm128_core(WkT + (size_t)m0 * 1024 + kc * 256,
                 WqT + (size_t)n0 * 1024 + kc * 256, 256, 1024, 1024,
                 acc, smem, smem + 4096);
    const int lane = tid & 63, wid = tid >> 6;
    const int wr = wid >> 1, wc = wid & 1;
    float* plane = MtP + (size_t)kc * 1024 * 1024;
#pragma unroll
    for (int mi = 0; mi < 4; ++mi)
#pragma unroll
      for (int ni = 0; ni < 4; ++ni)
#pragma unroll
        for (int j = 0; j < 4; ++j) {
          int row = m0 + (wr << 6) + mi * 16 + ((lane >> 4) << 2) + j;
          int col = n0 + (wc << 6) + ni * 16 + (lane & 15);
          plane[(size_t)row * 1024 + col] = acc[mi][ni][j];
        }
  }
}

// ---- Mt reduce: Mt = fp16( (P0+P1+P2+P3) / 32 )
__global__ __launch_bounds__(256) void mtred_kernel(const float* __restrict__ MtP,
                                                    u16* __restrict__ Mt) {
  const size_t i = (size_t)blockIdx.x * 1024 + threadIdx.x * 4;
  float4 a = *(const float4*)(MtP + i);
  float4 b = *(const float4*)(MtP + 1048576 + i);
  float4 cc = *(const float4*)(MtP + 2097152 + i);
  float4 d = *(const float4*)(MtP + 3145728 + i);
  u16x4 o;
  o[0] = f2h((a.x + b.x + cc.x + d.x) * 0.03125f);
  o[1] = f2h((a.y + b.y + cc.y + d.y) * 0.03125f);
  o[2] = f2h((a.z + b.z + cc.z + d.z) * 0.03125f);
  o[3] = f2h((a.w + b.w + cc.w + d.w) * 0.03125f);
  *(u16x4*)(Mt + i) = o;
}

// ---- merged G + vT (flat grid 512, XCD-swizzled, uniform NT=16)
__global__ __launch_bounds__(512) void proj256_kernel(const u16* __restrict__ emb16,
                                                      const u16* __restrict__ Mt,
                                                      const u16* __restrict__ Wv16,
                                                      const float* __restrict__ bv,
                                                      u16* __restrict__ G,
                                                      u16* __restrict__ vT) {
  __shared__ __align__(16) u16 sm[65536];
  const int wg = xcd_swz(blockIdx.x, 512);
  const int lane = threadIdx.x & 63, wid = threadIdx.x >> 6;
  f32x4 acc[8][4] = {};
  if (wg < 256) {
    const int m0 = (wg >> 2) * 256;
    const int n0 = (wg & 3) * 256;
    gemm256_core(emb16 + (size_t)m0 * 1024, Mt + (size_t)n0 * 1024, 16, 1024, 1024,
                 sm, acc);
    const int rb = m0 + ((wid >> 2) << 7) + ((lane >> 4) << 2);
    const int cb = n0 + ((wid & 3) << 6) + (lane & 15);
#pragma unroll
    for (int m = 0; m < 8; ++m)
#pragma unroll
      for (int n = 0; n < 4; ++n)
#pragma unroll
        for (int j = 0; j < 4; ++j)
          G[(size_t)(rb + m * 16 + j) * 1024 + (cb + n * 16)] = f2h(acc[m][n][j]);
  } else {
    const int r = wg - 256;
    const int m0 = (r & 3) * 256;   // d
    const int n0 = (r >> 2) * 256;  // global rows
    gemm256_core(Wv16 + (size_t)m0 * 1024, emb16 + (size_t)n0 * 1024, 16, 1024, 1024,
                 sm, acc);
    const int rb = m0 + ((wid >> 2) << 7) + ((lane >> 4) << 2);
    const int cb = n0 + ((wid & 3) << 6) + (lane & 15);
#pragma unroll
    for (int m = 0; m < 8; ++m)
#pragma unroll
      for (int n = 0; n < 4; ++n)
#pragma unroll
        for (int j = 0; j < 4; ++j) {
          int d = rb + m * 16 + j;
          int kg = cb + n * 16;
          int bi = kg >> 11, s = kg & 2047;
          vT[((size_t)bi << 21) + ((size_t)d << 11) + s] = f2h(acc[m][n][j] + bv[d]);
        }
  }
}

// ---- scores: scH = fp16( G·E^T + c_col )
__global__ __launch_bounds__(512) void scores256_kernel(const u16* __restrict__ G,
                                                        const u16* __restrict__ emb16,
                                                        const float* __restrict__ c,
                                                        u16* __restrict__ scH) {
  __shared__ __align__(16) u16 sm[65536];
  const int wg = xcd_swz(blockIdx.x, 512);
  const int b = wg >> 6;
  const int m0 = ((wg >> 3) & 7) * 256;
  const int n0 = (wg & 7) * 256;
  f32x4 acc[8][4] = {};
  gemm256_core(G + ((size_t)b * SEQ + m0) * DIM, emb16 + ((size_t)b * SEQ + n0) * DIM,
               16, DIM, DIM, sm, acc);
  const int lane = threadIdx.x & 63, wid = threadIdx.x >> 6;
  const int rb = m0 + ((wid >> 2) << 7) + ((lane >> 4) << 2);
  const int cb = n0 + ((wid & 3) << 6) + (lane & 15);
  float cn[4];
#pragma unroll
  for (int n = 0; n < 4; ++n) cn[n] = c[(size_t)b * SEQ + cb + n * 16];
#pragma unroll
  for (int m = 0; m < 8; ++m)
#pragma unroll
    for (int n = 0; n < 4; ++n)
#pragma unroll
      for (int j = 0; j < 4; ++j) {
        size_t idx = ((size_t)b * SEQ + rb + m * 16 + j) * SEQ + (cb + n * 16);
        scH[idx] = f2h(acc[m][n][j] + cn[n]);
      }
}

// ---- softmax: f = scH + mask/32 (fp32 math), probs fp16 in place
__global__ __launch_bounds__(256) void softmax_kernel(u16* __restrict__ scH,
                                                      const float* __restrict__ mask) {
  __shared__ float red[8];
  const size_t row = blockIdx.x;
  u16* rowp = scH + row * SEQ;
  const float* mrow = mask + row * SEQ;
  const int tid = threadIdx.x;
  short8 raw = *(const short8*)(rowp + tid * 8);
  float4 m0 = ((const float4*)mrow)[2 * tid];
  float4 m1 = ((const float4*)mrow)[2 * tid + 1];
  float mk[8] = {m0.x, m0.y, m0.z, m0.w, m1.x, m1.y, m1.z, m1.w};
  float f[8];
#pragma unroll
  for (int j = 0; j < 8; ++j) f[j] = h2f((u16)raw[j]) + mk[j] * 0.03125f;
  float mx = f[0];
#pragma unroll
  for (int j = 1; j < 8; ++j) mx = fmaxf(mx, f[j]);
#pragma unroll
  for (int off = 1; off < 64; off <<= 1) mx = fmaxf(mx, __shfl_xor(mx, off));
  const int wid = tid >> 6, lane = tid & 63;
  if (lane == 0) red[wid] = mx;
  __syncthreads();
  mx = fmaxf(fmaxf(red[0], red[1]), fmaxf(red[2], red[3]));
  float e[8];
  float s = 0.f;
#pragma unroll
  for (int j = 0; j < 8; ++j) {
    e[j] = __expf(f[j] - mx);
    s += e[j];
  }
#pragma unroll
  for (int off = 1; off < 64; off <<= 1) s += __shfl_xor(s, off);
  if (lane == 0) red[4 + wid] = s;
  __syncthreads();
  s = (red[4] + red[5]) + (red[6] + red[7]);
  const float inv = 1.f / s;
  short8 o;
#pragma unroll
  for (int j = 0; j < 8; ++j) o[j] = (short)f2h(e[j] * inv);
  *(short8*)(rowp + tid * 8) = o;
}

// ---- PV: out = probs @ v^T
__global__ __launch_bounds__(512) void pv256_kernel(const u16* __restrict__ pr,
                                                    const u16* __restrict__ vt,
                                                    float* __restrict__ out) {
  __shared__ __align__(16) u16 sm[65536];
  const int wg = xcd_swz(blockIdx.x, 256);
  const int b = wg >> 5;
  const int m0 = ((wg >> 2) & 7) * 256;
  const int n0 = (wg & 3) * 256;
  f32x4 acc[8][4] = {};
  gemm256_core(pr + ((size_t)b * SEQ + m0) * SEQ, vt + ((size_t)b * DIM + n0) * SEQ,
               32, SEQ, SEQ, sm, acc);
  const int lane = threadIdx.x & 63, wid = threadIdx.x >> 6;
  const int rb = m0 + ((wid >> 2) << 7) + ((lane >> 4) << 2);
  const int cb = n0 + ((wid & 3) << 6) + (lane & 15);
#pragma unroll
  for (int m = 0; m < 8; ++m)
#pragma unroll
    for (int n = 0; n < 4; ++n)
#pragma unroll
      for (int j = 0; j < 4; ++j)
        out[((size_t)b * SEQ + rb + m * 16 + j) * DIM + (cb + n * 16)] = acc[m][n][j];
}

extern "C" void kernel_launch(void* const* d_in, const int* in_sizes, int n_in,
                              void* d_out, int out_size, void* d_ws, size_t ws_size,
                              hipStream_t stream) {
  const float* emb  = (const float*)d_in[0];
  const float* mask = (const float*)d_in[1];
  const float* Wq   = (const float*)d_in[2];
  const float* bq   = (const float*)d_in[3];
  const float* Wk   = (const float*)d_in[4];
  const float* bk   = (const float*)d_in[5];  // unused: row-terms cancel in softmax
  const float* Wv   = (const float*)d_in[6];
  const float* bv   = (const float*)d_in[7];
  float* out = (float*)d_out;
  (void)bk;

  const size_t M1 = 1024 * 1024;
  u16* scH   = (u16*)d_ws;              // 32M u16
  u16* emb16 = scH + 32 * M1;           // 16M
  u16* WqT   = emb16 + 16 * M1;         // 1M
  u16* WkT   = WqT + M1;                // 1M
  u16* Wv16  = WkT + M1;                // 1M
  u16* Mt    = Wv16 + M1;               // 1M
  u16* G     = Mt + M1;                 // 16M
  u16* vT    = G + 16 * M1;             // 16M
  float* MtP = (float*)(vT + 16 * M1);  // 4M fp32
  float* w   = MtP + 4 * M1;            // 1K fp32
  float* c   = w + 1024;                // 16K fp32

  prep_kernel<<<17952, 256, 0, stream>>>(emb, Wq, Wk, Wv, bq, emb16, WqT, WkT, Wv16, w);
  cmt_kernel<<<4352, 256, 0, stream>>>(emb16, WqT, WkT, w, c, MtP);
  mtred_kernel<<<1024, 256, 0, stream>>>(MtP, Mt);

  proj256_kernel<<<512, 512, 0, stream>>>(emb16, Mt, Wv16, bv, G, vT);

  scores256_kernel<<<512, 512, 0, stream>>>(G, emb16, c, scH);
  softmax_kernel<<<MROWS, 256, 0, stream>>>(scH, mask);
  pv256_kernel<<<256, 512, 0, stream>>>((const u16*)scH, vT, out);
}

// Round 18
// 296.785 us; speedup vs baseline: 1.0636x; 1.0023x over previous
//
#include <hip/hip_runtime.h>

// SelfAttention: B=8, S=2048, D=1024, fp32 in/out — ALL-FP16 MFMA pipeline.
// Algebra: S/32 = E·Mt^T·E^T + c_j, Mt[f][e] = (sum_c Wk[c][f]Wq[c][e])/32,
// c = E·(Wk^T bq)/32; per-row terms cancel in softmax (q/k projections removed).
// Core: 256x256-tile 8-wave BK=64 double-buffered, per-phase barriers (r13
// structure) — MFMA now via __builtin_amdgcn_mfma_f32_16x16x32_f16 (NOT inline
// asm) so LLVM can model MFMA latency, interleave ds_reads, schedule natively.
// Waits: entry vmcnt(2), mid vmcnt(4). Swizzled LDS via pre-swizzled global
// staging; XCD-chunked block swizzle.
// Setup: mega-prep (cvts + non-atomic w GEMV), split-K Mt + c GEMV, tiny reduce.
// scores: fp16 s/32 logits; softmax adds mask/32 (fp32); PV fp16 MFMA, fp32 out.
// d_ws (u16): scH[32M] | emb16[16M] | WqT[1M] WkT[1M] Wv16[1M] Mt[1M] |
//   G[16M] vT[16M] | MtP fp32[4M] | w[1K f32] c[16K f32].

#define B_SZ 8
#define SEQ  2048
#define DIM  1024
#define MROWS (B_SZ * SEQ)  // 16384

typedef unsigned short u16;
typedef short short8 __attribute__((ext_vector_type(8)));
typedef _Float16 half8 __attribute__((ext_vector_type(8)));
typedef unsigned short u16x4 __attribute__((ext_vector_type(4)));
typedef float f32x4 __attribute__((ext_vector_type(4)));

__device__ __forceinline__ u16 f2h(float x) {
  _Float16 h = (_Float16)x;
  union { _Float16 f; u16 u; } c; c.f = h; return c.u;
}
__device__ __forceinline__ float h2f(u16 u) {
  union { _Float16 f; u16 u; } c; c.u = u; return (float)c.f;
}

__device__ __forceinline__ int xcd_swz(int x, int nwg) {
  return (x & 7) * (nwg >> 3) + (x >> 3);
}

__device__ __forceinline__ void gload_lds16(const u16* g, u16* l) {
  __builtin_amdgcn_global_load_lds(
      (__attribute__((address_space(1))) void*)(g),
      (__attribute__((address_space(3))) void*)(l), 16, 0, 0);
}

// MFMA via builtin: LLVM models latency, interleaves, allocates AGPRs natively.
__device__ __forceinline__ f32x4 mfma_f16(short8 a, short8 b, f32x4 c) {
  return __builtin_amdgcn_mfma_f32_16x16x32_f16(
      __builtin_bit_cast(half8, a), __builtin_bit_cast(half8, b), c, 0, 0, 0);
}

// ================= 256x256 8-wave GEMM core (fp16), per-phase barriers ======
// Consumption: ph0/1 need B*,A0(wm0)/A2(wm1); ph2/3 need A1(wm0)/A3(wm1).
// Next-tile issue: ph0 B0,B1 | ph1 B2,B3 | ph2 A0,A2 | ph3 A1,A3 (FIFO).
// Waits: entry vmcnt(2) (own A1,A3 may fly); pre-ph2 vmcnt(4) when prefetching
// (allows the 4 new B loads; forces old A1,A3 landed), else vmcnt(0).
#define PHASE_MFMA(mb, af)                                        \
  __builtin_amdgcn_s_setprio(1);                                  \
  _Pragma("unroll")                                               \
  for (int h = 0; h < 2; ++h)                                     \
    _Pragma("unroll")                                             \
    for (int m = 0; m < 2; ++m)                                   \
      _Pragma("unroll")                                           \
      for (int n = 0; n < 4; ++n)                                 \
        acc[(mb) + m][n] = mfma_f16(af[m][h], bf[n][h], acc[(mb) + m][n]); \
  __builtin_amdgcn_s_setprio(0)

__device__ __forceinline__ void gemm256_core(const u16* __restrict__ Ag,
                                             const u16* __restrict__ Bg,
                                             int NT, size_t lda, size_t ldb,
                                             u16* sm, f32x4 (&acc)[8][4]) {
  const int tid = threadIdx.x;
  const int lane = tid & 63;
  const int wid = tid >> 6;
  const int wm8 = (wid >> 2) << 3;
  const int wn4 = (wid & 3) << 2;

  u16* sA = sm;
  u16* sB = sm + 32768;

  const int bb = (lane << 4) ^ (((lane >> 5) & 1) << 5);
  const int rins = bb >> 6;
  const int cins = (bb & 63) >> 1;
  const int s0 = wid, s1 = 8 + wid, s2 = 16 + wid, s3 = 24 + wid;
  const size_t aoff0 = (size_t)((s0 >> 1) * 16 + rins) * lda + ((s0 & 1) * 32 + cins);
  const size_t aoff1 = (size_t)((s1 >> 1) * 16 + rins) * lda + ((s1 & 1) * 32 + cins);
  const size_t aoff2 = (size_t)((s2 >> 1) * 16 + rins) * lda + ((s2 & 1) * 32 + cins);
  const size_t aoff3 = (size_t)((s3 >> 1) * 16 + rins) * lda + ((s3 & 1) * 32 + cins);
  const size_t boff0 = (size_t)((s0 >> 1) * 16 + rins) * ldb + ((s0 & 1) * 32 + cins);
  const size_t boff1 = (size_t)((s1 >> 1) * 16 + rins) * ldb + ((s1 & 1) * 32 + cins);
  const size_t boff2 = (size_t)((s2 >> 1) * 16 + rins) * ldb + ((s2 & 1) * 32 + cins);
  const size_t boff3 = (size_t)((s3 >> 1) * 16 + rins) * ldb + ((s3 & 1) * 32 + cins);
  const int wid512 = wid << 9;

  const int lof = ((lane & 15) << 6) + ((lane >> 4) << 4);
  const int loe = (lof ^ (((lane >> 3) & 1) << 5)) >> 1;

#define ISSUE_A(j, nb, kt) \
  gload_lds16(Ag + aoff##j + (size_t)(kt) * 64, sA + (nb) * 16384 + (j) * 4096 + wid512)
#define ISSUE_B(j, nb, kt) \
  gload_lds16(Bg + boff##j + (size_t)(kt) * 64, sB + (nb) * 16384 + (j) * 4096 + wid512)

  // prologue: stage tile 0 into buf 0 in steady-state FIFO order
  ISSUE_B(0, 0, 0); ISSUE_B(1, 0, 0); ISSUE_B(2, 0, 0); ISSUE_B(3, 0, 0);
  ISSUE_A(0, 0, 0); ISSUE_A(2, 0, 0); ISSUE_A(1, 0, 0); ISSUE_A(3, 0, 0);

  int buf = 0;
  for (int kt = 0; kt < NT; ++kt) {
    const int nk = kt + 1;
    const bool pre = nk < NT;
    const int nb = buf ^ 1;
    // tile entry: B0-3, A0, A2 landed (all waves); own A1,A3 may fly
    asm volatile("s_waitcnt vmcnt(2)" ::: "memory");
    __builtin_amdgcn_s_barrier();
    asm volatile("" ::: "memory");
    const u16* bufA = sA + buf * 16384;
    const u16* bufB = sB + buf * 16384;
    short8 bf[4][2];
    // ---- phase 0: reads bf + A(m0,m1); issue B0,B1; MFMA m0,m1
    {
#pragma unroll
      for (int n = 0; n < 4; ++n) {
        bf[n][0] = *(const short8*)(bufB + (wn4 + n) * 1024 + loe);
        bf[n][1] = *(const short8*)(bufB + (wn4 + n) * 1024 + 512 + loe);
      }
      short8 af[2][2];
#pragma unroll
      for (int m = 0; m < 2; ++m) {
        af[m][0] = *(const short8*)(bufA + (wm8 + m) * 1024 + loe);
        af[m][1] = *(const short8*)(bufA + (wm8 + m) * 1024 + 512 + loe);
      }
      if (pre) { ISSUE_B(0, nb, nk); ISSUE_B(1, nb, nk); }
      PHASE_MFMA(0, af);
    }
    __builtin_amdgcn_s_barrier();
    asm volatile("" ::: "memory");
    // ---- phase 1: reads A(m2,m3); issue B2,B3; MFMA m2,m3
    {
      short8 af[2][2];
#pragma unroll
      for (int m = 0; m < 2; ++m) {
        af[m][0] = *(const short8*)(bufA + (wm8 + 2 + m) * 1024 + loe);
        af[m][1] = *(const short8*)(bufA + (wm8 + 2 + m) * 1024 + 512 + loe);
      }
      if (pre) { ISSUE_B(2, nb, nk); ISSUE_B(3, nb, nk); }
      PHASE_MFMA(2, af);
    }
    // mid-tile: old A1,A3 must land for ph2/3 reads (all waves)
    if (pre) {
      asm volatile("s_waitcnt vmcnt(4)" ::: "memory");
    } else {
      asm volatile("s_waitcnt vmcnt(0)" ::: "memory");
    }
    __builtin_amdgcn_s_barrier();
    asm volatile("" ::: "memory");
    // ---- phase 2: reads A(m4,m5); issue A0,A2; MFMA m4,m5
    {
      short8 af[2][2];
#pragma unroll
      for (int m = 0; m < 2; ++m) {
        af[m][0] = *(const short8*)(bufA + (wm8 + 4 + m) * 1024 + loe);
        af[m][1] = *(const short8*)(bufA + (wm8 + 4 + m) * 1024 + 512 + loe);
      }
      if (pre) { ISSUE_A(0, nb, nk); ISSUE_A(2, nb, nk); }
      PHASE_MFMA(4, af);
    }
    __builtin_amdgcn_s_barrier();
    asm volatile("" ::: "memory");
    // ---- phase 3: reads A(m6,m7); issue A1,A3; MFMA m6,m7
    {
      short8 af[2][2];
#pragma unroll
      for (int m = 0; m < 2; ++m) {
        af[m][0] = *(const short8*)(bufA + (wm8 + 6 + m) * 1024 + loe);
        af[m][1] = *(const short8*)(bufA + (wm8 + 6 + m) * 1024 + 512 + loe);
      }
      if (pre) { ISSUE_A(1, nb, nk); ISSUE_A(3, nb, nk); }
      PHASE_MFMA(6, af);
    }
    buf ^= 1;
  }
  asm volatile("s_nop 7\n\ts_nop 7\n\ts_nop 7" ::);
#undef ISSUE_A
#undef ISSUE_B
}

// ======== 128x128 4-wave core (r0-verified structure, f16) ===================
__device__ __forceinline__ void gemm128_core(const u16* A, const u16* Bt, int K,
                                             int lda, int ldb, f32x4 (&acc)[4][4],
                                             u16* sA, u16* sB) {
  const int tid = threadIdx.x;
  const int lane = tid & 63;
  const int wid = tid >> 6;
  const int wr = wid >> 1;
  const int wc = wid & 1;
  const int srow = tid >> 2;
  const int scol = (tid & 3) << 3;
  const u16* ga0 = A + (size_t)srow * lda + scol;
  const u16* ga1 = A + (size_t)(srow + 64) * lda + scol;
  const u16* gb0 = Bt + (size_t)srow * ldb + scol;
  const u16* gb1 = Bt + (size_t)(srow + 64) * ldb + scol;
  u16* la0 = sA + (wid << 9);
  u16* la1 = sA + 2048 + (wid << 9);
  u16* lb0 = sB + (wid << 9);
  u16* lb1 = sB + 2048 + (wid << 9);
  const u16* pa = sA + (size_t)((wr << 6) + (lane & 15)) * 32 + ((lane >> 4) << 3);
  const u16* pb = sB + (size_t)((wc << 6) + (lane & 15)) * 32 + ((lane >> 4) << 3);
  const int ksteps = K >> 5;
  for (int kt = 0; kt < ksteps; ++kt) {
    gload_lds16(ga0, la0);
    gload_lds16(ga1, la1);
    gload_lds16(gb0, lb0);
    gload_lds16(gb1, lb1);
    ga0 += 32; ga1 += 32; gb0 += 32; gb1 += 32;
    __syncthreads();
    short8 a[4], b[4];
#pragma unroll
    for (int i = 0; i < 4; ++i) a[i] = *(const short8*)(pa + (i << 9));
#pragma unroll
    for (int i = 0; i < 4; ++i) b[i] = *(const short8*)(pb + (i << 9));
#pragma unroll
    for (int mi = 0; mi < 4; ++mi)
#pragma unroll
      for (int ni = 0; ni < 4; ++ni)
        acc[mi][ni] = mfma_f16(a[mi], b[ni], acc[mi][ni]);
    __syncthreads();
  }
  asm volatile("s_nop 7\n\ts_nop 7\n\ts_nop 7" ::);
}

// ---- MEGA-PREP (grid 17952): emb cvt | WqT/WkT transpose-cvt | Wv cvt |
//      w GEMV (32 blocks, non-atomic: 8 row-groups x 32 e-lanes, LDS reduce)
__global__ __launch_bounds__(256) void prep_kernel(const float* __restrict__ emb,
                                                   const float* __restrict__ Wq,
                                                   const float* __restrict__ Wk,
                                                   const float* __restrict__ Wv,
                                                   const float* __restrict__ bq,
                                                   u16* __restrict__ emb16,
                                                   u16* __restrict__ WqT,
                                                   u16* __restrict__ WkT,
                                                   u16* __restrict__ Wv16,
                                                   float* __restrict__ w) {
  __shared__ float t[64][65];
  const int b = blockIdx.x;
  const int tid = threadIdx.x;
  if (b < 16384) {
    int i = b * 256 + tid;
    float4 v = ((const float4*)emb)[i];
    u16x4 o;
    o[0] = f2h(v.x); o[1] = f2h(v.y); o[2] = f2h(v.z); o[3] = f2h(v.w);
    ((u16x4*)emb16)[i] = o;
  } else if (b < 16896) {
    const int b2 = b - 16384;
    const float* src = (b2 >> 8) ? Wk : Wq;
    u16* dst = (b2 >> 8) ? WkT : WqT;
    const int rem = b2 & 255;
    const int r0 = (rem >> 4) * 64;
    const int c0 = (rem & 15) * 64;
    const int tr = tid >> 4;
    const int c4 = (tid & 15) << 2;
#pragma unroll
    for (int i = 0; i < 4; ++i) {
      float4 x = *(const float4*)(src + (size_t)(r0 + tr + 16 * i) * 1024 + c0 + c4);
      t[tr + 16 * i][c4 + 0] = x.x;
      t[tr + 16 * i][c4 + 1] = x.y;
      t[tr + 16 * i][c4 + 2] = x.z;
      t[tr + 16 * i][c4 + 3] = x.w;
    }
    __syncthreads();
#pragma unroll
    for (int i = 0; i < 4; ++i) {
      int dr = tr + 16 * i;
      u16x4 y;
      y[0] = f2h(t[c4 + 0][dr]);
      y[1] = f2h(t[c4 + 1][dr]);
      y[2] = f2h(t[c4 + 2][dr]);
      y[3] = f2h(t[c4 + 3][dr]);
      *(u16x4*)(dst + (size_t)(c0 + dr) * 1024 + r0 + c4) = y;
    }
  } else if (b < 17920) {
    int i = (b - 16896) * 256 + tid;
    float4 v = ((const float4*)Wv)[i];
    u16x4 o;
    o[0] = f2h(v.x); o[1] = f2h(v.y); o[2] = f2h(v.z); o[3] = f2h(v.w);
    ((u16x4*)Wv16)[i] = o;
  } else {
    // w GEMV, non-atomic: block owns e in [wb*32, wb*32+32); 8 row-groups.
    const int wb = b - 17920;          // 0..31
    const int el = tid & 31;           // e-lane
    const int rg = tid >> 5;           // 0..7
    const int e = wb * 32 + el;
    float s = 0.f;
    const float* col = Wk + e;
#pragma unroll 4
    for (int r = rg * 128; r < rg * 128 + 128; ++r)
      s += col[(size_t)r * 1024] * bq[r];
    float* red = &t[0][0];             // reuse shared (branch-exclusive)
    red[rg * 32 + el] = s;
    __syncthreads();
    if (tid < 32) {
      float a = 0.f;
#pragma unroll
      for (int g = 0; g < 8; ++g) a += red[g * 32 + tid];
      w[wb * 32 + tid] = a * 0.03125f;
    }
  }
}

// ---- launch 2 (grid 4352): c GEMV (wave-per-row) | Mt split-K partials
__global__ __launch_bounds__(256) void cmt_kernel(const u16* __restrict__ emb16,
                                                  const u16* __restrict__ WqT,
                                                  const u16* __restrict__ WkT,
                                                  const float* __restrict__ w,
                                                  float* __restrict__ c,
                                                  float* __restrict__ MtP) {
  __shared__ __align__(16) u16 smem[8192];
  const int b = blockIdx.x;
  const int tid = threadIdx.x;
  if (b < 4096) {
    float* sw = (float*)smem;
    for (int i = tid; i < 1024; i += 256) sw[i] = w[i];
    __syncthreads();
    const int wv = tid >> 6, lane = tid & 63;
    const int r = b * 4 + wv;
    const u16* row = emb16 + (size_t)r * 1024;
    float s = 0.f;
#pragma unroll
    for (int it = 0; it < 2; ++it) {
      int d = lane * 8 + it * 512;
      short8 v = *(const short8*)(row + d);
#pragma unroll
      for (int j = 0; j < 8; ++j) s += h2f((u16)v[j]) * sw[d + j];
    }
#pragma unroll
    for (int off = 1; off < 64; off <<= 1) s += __shfl_xor(s, off);
    if (lane == 0) c[r] = s;
  } else {
    const int b2 = b - 4096;
    const int tile = b2 >> 2;
    const int kc = b2 & 3;
    const int m0 = (tile >> 3) * 128;
    const int n0 = (tile & 7) * 128;
    f32x4 acc[4][4] = {};
    gemm128_core(WkT + (size_t)m0 * 1024 + kc * 256,
                 WqT + (size_t)n0 * 1024 + kc * 256, 256, 1024, 1024,
                 acc, smem, smem + 4096);
    const int lane = tid & 63, wid = tid >> 6;
    const int wr = wid >> 1, wc = wid & 1;
    float* plane = MtP + (size_t)kc * 1024 * 1024;
#pragma unroll
    for (int mi = 0; mi < 4; ++mi)
#pragma unroll
      for (int ni = 0; ni < 4; ++ni)
#pragma unroll
        for (int j = 0; j < 4; ++j) {
          int row = m0 + (wr << 6) + mi * 16 + ((lane >> 4) << 2) + j;
          int col = n0 + (wc << 6) + ni * 16 + (lane & 15);
          plane[(size_t)row * 1024 + col] = acc[mi][ni][j];
        }
  }
}

// ---- Mt reduce: Mt = fp16( (P0+P1+P2+P3) / 32 )
__global__ __launch_bounds__(256) void mtred_kernel(const float* __restrict__ MtP,
                                                    u16* __restrict__ Mt) {
  const size_t i = (size_t)blockIdx.x * 1024 + threadIdx.x * 4;
  float4 a = *(const float4*)(MtP + i);
  float4 b = *(const float4*)(MtP + 1048576 + i);
  float4 cc = *(const float4*)(MtP + 2097152 + i);
  float4 d = *(const float4*)(MtP + 3145728 + i);
  u16x4 o;
  o[0] = f2h((a.x + b.x + cc.x + d.x) * 0.03125f);
  o[1] = f2h((a.y + b.y + cc.y + d.y) * 0.03125f);
  o[2] = f2h((a.z + b.z + cc.z + d.z) * 0.03125f);
  o[3] = f2h((a.w + b.w + cc.w + d.w) * 0.03125f);
  *(u16x4*)(Mt + i) = o;
}

// ---- merged G + vT (flat grid 512, XCD-swizzled, uniform NT=16)
__global__ __launch_bounds__(512) void proj256_kernel(const u16* __restrict__ emb16,
                                                      const u16* __restrict__ Mt,
                                                      const u16* __restrict__ Wv16,
                                                      const float* __restrict__ bv,
                                                      u16* __restrict__ G,
                                                      u16* __restrict__ vT) {
  __shared__ __align__(16) u16 sm[65536];
  const int wg = xcd_swz(blockIdx.x, 512);
  const int lane = threadIdx.x & 63, wid = threadIdx.x >> 6;
  f32x4 acc[8][4] = {};
  if (wg < 256) {
    const int m0 = (wg >> 2) * 256;
    const int n0 = (wg & 3) * 256;
    gemm256_core(emb16 + (size_t)m0 * 1024, Mt + (size_t)n0 * 1024, 16, 1024, 1024,
                 sm, acc);
    const int rb = m0 + ((wid >> 2) << 7) + ((lane >> 4) << 2);
    const int cb = n0 + ((wid & 3) << 6) + (lane & 15);
#pragma unroll
    for (int m = 0; m < 8; ++m)
#pragma unroll
      for (int n = 0; n < 4; ++n)
#pragma unroll
        for (int j = 0; j < 4; ++j)
          G[(size_t)(rb + m * 16 + j) * 1024 + (cb + n * 16)] = f2h(acc[m][n][j]);
  } else {
    const int r = wg - 256;
    const int m0 = (r & 3) * 256;   // d
    const int n0 = (r >> 2) * 256;  // global rows
    gemm256_core(Wv16 + (size_t)m0 * 1024, emb16 + (size_t)n0 * 1024, 16, 1024, 1024,
                 sm, acc);
    const int rb = m0 + ((wid >> 2) << 7) + ((lane >> 4) << 2);
    const int cb = n0 + ((wid & 3) << 6) + (lane & 15);
#pragma unroll
    for (int m = 0; m < 8; ++m)
#pragma unroll
      for (int n = 0; n < 4; ++n)
#pragma unroll
        for (int j = 0; j < 4; ++j) {
          int d = rb + m * 16 + j;
          int kg = cb + n * 16;
          int bi = kg >> 11, s = kg & 2047;
          vT[((size_t)bi << 21) + ((size_t)d << 11) + s] = f2h(acc[m][n][j] + bv[d]);
        }
  }
}

// ---- scores: scH = fp16( G·E^T + c_col )
__global__ __launch_bounds__(512) void scores256_kernel(const u16* __restrict__ G,
                                                        const u16* __restrict__ emb16,
                                                        const float* __restrict__ c,
                                                        u16* __restrict__ scH) {
  __shared__ __align__(16) u16 sm[65536];
  const int wg = xcd_swz(blockIdx.x, 512);
  const int b = wg >> 6;
  const int m0 = ((wg >> 3) & 7) * 256;
  const int n0 = (wg & 7) * 256;
  f32x4 acc[8][4] = {};
  gemm256_core(G + ((size_t)b * SEQ + m0) * DIM, emb16 + ((size_t)b * SEQ + n0) * DIM,
               16, DIM, DIM, sm, acc);
  const int lane = threadIdx.x & 63, wid = threadIdx.x >> 6;
  const int rb = m0 + ((wid >> 2) << 7) + ((lane >> 4) << 2);
  const int cb = n0 + ((wid & 3) << 6) + (lane & 15);
  float cn[4];
#pragma unroll
  for (int n = 0; n < 4; ++n) cn[n] = c[(size_t)b * SEQ + cb + n * 16];
#pragma unroll
  for (int m = 0; m < 8; ++m)
#pragma unroll
    for (int n = 0; n < 4; ++n)
#pragma unroll
      for (int j = 0; j < 4; ++j) {
        size_t idx = ((size_t)b * SEQ + rb + m * 16 + j) * SEQ + (cb + n * 16);
        scH[idx] = f2h(acc[m][n][j] + cn[n]);
      }
}

// ---- softmax: f = scH + mask/32 (fp32 math), probs fp16 in place
__global__ __launch_bounds__(256) void softmax_kernel(u16* __restrict__ scH,
                                                      const float* __restrict__ mask) {
  __shared__ float red[8];
  const size_t row = blockIdx.x;
  u16* rowp = scH + row * SEQ;
  const float* mrow = mask + row * SEQ;
  const int tid = threadIdx.x;
  short8 raw = *(const short8*)(rowp + tid * 8);
  float4 m0 = ((const float4*)mrow)[2 * tid];
  float4 m1 = ((const float4*)mrow)[2 * tid + 1];
  float mk[8] = {m0.x, m0.y, m0.z, m0.w, m1.x, m1.y, m1.z, m1.w};
  float f[8];
#pragma unroll
  for (int j = 0; j < 8; ++j) f[j] = h2f((u16)raw[j]) + mk[j] * 0.03125f;
  float mx = f[0];
#pragma unroll
  for (int j = 1; j < 8; ++j) mx = fmaxf(mx, f[j]);
#pragma unroll
  for (int off = 1; off < 64; off <<= 1) mx = fmaxf(mx, __shfl_xor(mx, off));
  const int wid = tid >> 6, lane = tid & 63;
  if (lane == 0) red[wid] = mx;
  __syncthreads();
  mx = fmaxf(fmaxf(red[0], red[1]), fmaxf(red[2], red[3]));
  float e[8];
  float s = 0.f;
#pragma unroll
  for (int j = 0; j < 8; ++j) {
    e[j] = __expf(f[j] - mx);
    s += e[j];
  }
#pragma unroll
  for (int off = 1; off < 64; off <<= 1) s += __shfl_xor(s, off);
  if (lane == 0) red[4 + wid] = s;
  __syncthreads();
  s = (red[4] + red[5]) + (red[6] + red[7]);
  const float inv = 1.f / s;
  short8 o;
#pragma unroll
  for (int j = 0; j < 8; ++j) o[j] = (short)f2h(e[j] * inv);
  *(short8*)(rowp + tid * 8) = o;
}

// ---- PV: out = probs @ v^T
__global__ __launch_bounds__(512) void pv256_kernel(const u16* __restrict__ pr,
                                                    const u16* __restrict__ vt,
                                                    float* __restrict__ out) {
  __shared__ __align__(16) u16 sm[65536];
  const int wg = xcd_swz(blockIdx.x, 256);
  const int b = wg >> 5;
  const int m0 = ((wg >> 2) & 7) * 256;
  const int n0 = (wg & 3) * 256;
  f32x4 acc[8][4] = {};
  gemm256_core(pr + ((size_t)b * SEQ + m0) * SEQ, vt + ((size_t)b * DIM + n0) * SEQ,
               32, SEQ, SEQ, sm, acc);
  const int lane = threadIdx.x & 63, wid = threadIdx.x >> 6;
  const int rb = m0 + ((wid >> 2) << 7) + ((lane >> 4) << 2);
  const int cb = n0 + ((wid & 3) << 6) + (lane & 15);
#pragma unroll
  for (int m = 0; m < 8; ++m)
#pragma unroll
    for (int n = 0; n < 4; ++n)
#pragma unroll
      for (int j = 0; j < 4; ++j)
        out[((size_t)b * SEQ + rb + m * 16 + j) * DIM + (cb + n * 16)] = acc[m][n][j];
}

extern "C" void kernel_launch(void* const* d_in, const int* in_sizes, int n_in,
                              void* d_out, int out_size, void* d_ws, size_t ws_size,
                              hipStream_t stream) {
  const float* emb  = (const float*)d_in[0];
  const float* mask = (const float*)d_in[1];
  const float* Wq   = (const float*)d_in[2];
  const float* bq   = (const float*)d_in[3];
  const float* Wk   = (const float*)d_in[4];
  const float* bk   = (const float*)d_in[5];  // unused: row-terms cancel in softmax
  const float* Wv   = (const float*)d_in[6];
  const float* bv   = (const float*)d_in[7];
  float* out = (float*)d_out;
  (void)bk;

  const size_t M1 = 1024 * 1024;
  u16* scH   = (u16*)d_ws;              // 32M u16
  u16* emb16 = scH + 32 * M1;           // 16M
  u16* WqT   = emb16 + 16 * M1;         // 1M
  u16* WkT   = WqT + M1;                // 1M
  u16* Wv16  = WkT + M1;                // 1M
  u16* Mt    = Wv16 + M1;               // 1M
  u16* G     = Mt + M1;                 // 16M
  u16* vT    = G + 16 * M1;             // 16M
  float* MtP = (float*)(vT + 16 * M1);  // 4M fp32
  float* w   = MtP + 4 * M1;            // 1K fp32
  float* c   = w + 1024;                // 16K fp32

  prep_kernel<<<17952, 256, 0, stream>>>(emb, Wq, Wk, Wv, bq, emb16, WqT, WkT, Wv16, w);
  cmt_kernel<<<4352, 256, 0, stream>>>(emb16, WqT, WkT, w, c, MtP);
  mtred_kernel<<<1024, 256, 0, stream>>>(MtP, Mt);

  proj256_kernel<<<512, 512, 0, stream>>>(emb16, Mt, Wv16, bv, G, vT);

  scores256_kernel<<<512, 512, 0, stream>>>(G, emb16, c, scH);
  softmax_kernel<<<MROWS, 256, 0, stream>>>(scH, mask);
  pv256_kernel<<<256, 512, 0, stream>>>((const u16*)scH, vT, out);
}